// Round 1
// baseline (370.399 us; speedup 1.0000x reference)
//
#include <hip/hip_runtime.h>

// EdgeNetwork: out = segment_sum( (bond@K + bias).reshape(E,32,32) @ atom[pair[:,1]], pair[:,0] )
// Formulated as OUT = P @ W with P[e, b*32+j] = bond[e,b]*nb[e,j] (b=16 row block is
// the bias with implicit bond=1), W[(b,j), i] = K[b, i*32+j] resident in LDS.

constexpr int ATOM_DIM = 32;
constexpr int BOND_DIM = 16;
constexpr int NEDGE = 400000;
constexpr int TE = 128;            // edges per tile
constexpr int NTILES = NEDGE / TE; // 3125 exact
constexpr int CPB = 16;            // cols per block (each block owns half the 32 cols)
constexpr int KROWS = BOND_DIM * ATOM_DIM + ATOM_DIM; // 512 kernel rows + 32 bias rows

__global__ void zero_out(float* __restrict__ out, int n) {
  int i = blockIdx.x * blockDim.x + threadIdx.x;
  if (i < n) out[i] = 0.0f;
}

__global__ __launch_bounds__(256, 2)
void edge_kernel(const float* __restrict__ atom,
                 const float* __restrict__ bondf,
                 const int* __restrict__ pairs,
                 const float* __restrict__ Kmat,
                 const float* __restrict__ bias,
                 float* __restrict__ out) {
  __shared__ float Ws[KROWS * CPB];                 // 34816 B
  __shared__ float bondS[BOND_DIM * (TE + 2)];      // 8320 B, padded stride vs bank conflicts
  const int tid = threadIdx.x;
  const int colhalf = blockIdx.x & 1;               // which 16-col half this block computes
  const int c0g = colhalf * CPB;

  // Stage W (and bias rows) once per block. Ws[k*CPB + ci] = W[k][c0g+ci].
  for (int idx = tid; idx < KROWS * CPB; idx += 256) {
    const int k = idx >> 4;          // K-row 0..543
    const int ci = idx & (CPB - 1);  // local col
    const int i = c0g + ci;          // global output col
    float v;
    if (k < 512) {
      const int b = k >> 5, j = k & 31;
      v = Kmat[b * 1024 + i * 32 + j];
    } else {
      const int j = k - 512;
      v = bias[i * 32 + j];
    }
    Ws[idx] = v;
  }

  const int eg = tid >> 2;   // 0..63  (edge group: 2 edges each)
  const int cg = tid & 3;    // 0..3   (col group: 4 cols each)
  const int c0 = cg * 4;

  const int nstream = gridDim.x >> 1;
  for (int tile = blockIdx.x >> 1; tile < NTILES; tile += nstream) {
    __syncthreads();  // covers Ws writes (iter 0) and prior reads of bondS (iter >0)
    const int ebase = tile * TE;
    // Stage bond transposed: bondS[b][el]
    for (int idx = tid; idx < TE * BOND_DIM; idx += 256) {
      const int el = idx >> 4;
      const int b = idx & 15;
      bondS[b * (TE + 2) + el] = bondf[(size_t)(ebase + el) * BOND_DIM + b];
    }
    __syncthreads();

    const int el0 = eg * 2;
    const int e0 = ebase + el0;
    const int a0 = pairs[2 * e0 + 1];
    const int a1 = pairs[2 * e0 + 3];
    const int s0 = pairs[2 * e0 + 0];
    const int s1 = pairs[2 * e0 + 2];

    // Neighbor rows in registers (fully-unrolled accesses -> SROA, no scratch)
    float nAf[32], nBf[32];
    {
      const float4* ra = (const float4*)(atom + (size_t)a0 * ATOM_DIM);
      const float4* rb = (const float4*)(atom + (size_t)a1 * ATOM_DIM);
      #pragma unroll
      for (int q = 0; q < 8; ++q) {
        float4 t = ra[q];
        nAf[4*q+0]=t.x; nAf[4*q+1]=t.y; nAf[4*q+2]=t.z; nAf[4*q+3]=t.w;
        float4 u = rb[q];
        nBf[4*q+0]=u.x; nBf[4*q+1]=u.y; nBf[4*q+2]=u.z; nBf[4*q+3]=u.w;
      }
    }

    float acc0[4] = {0.f,0.f,0.f,0.f};
    float acc1[4] = {0.f,0.f,0.f,0.f};

    for (int b = 0; b < BOND_DIM + 1; ++b) {   // b==16 -> bias rows, bond weight 1.0
      float bb0 = 1.0f, bb1 = 1.0f;
      if (b < BOND_DIM) {
        bb0 = bondS[b * (TE + 2) + el0];
        bb1 = bondS[b * (TE + 2) + el0 + 1];
      }
      const float* wrow = &Ws[(b * 32) * CPB + c0];
      #pragma unroll
      for (int j = 0; j < 32; ++j) {
        const float4 w = *(const float4*)(wrow + j * CPB);  // ds_read_b128
        const float aA = bb0 * nAf[j];
        const float aB = bb1 * nBf[j];
        acc0[0] += aA * w.x; acc0[1] += aA * w.y;
        acc0[2] += aA * w.z; acc0[3] += aA * w.w;
        acc1[0] += aB * w.x; acc1[1] += aB * w.y;
        acc1[2] += aB * w.z; acc1[3] += aB * w.w;
      }
    }

    float* o0 = out + (size_t)s0 * ATOM_DIM + c0g + c0;
    float* o1 = out + (size_t)s1 * ATOM_DIM + c0g + c0;
    #pragma unroll
    for (int r = 0; r < 4; ++r) atomicAdd(o0 + r, acc0[r]);
    #pragma unroll
    for (int r = 0; r < 4; ++r) atomicAdd(o1 + r, acc1[r]);
  }
}

extern "C" void kernel_launch(void* const* d_in, const int* in_sizes, int n_in,
                              void* d_out, int out_size, void* d_ws, size_t ws_size,
                              hipStream_t stream) {
  const float* atom  = (const float*)d_in[0];   // (100000, 32) f32
  const float* bondf = (const float*)d_in[1];   // (400000, 16) f32
  const int*   pairs = (const int*)d_in[2];     // (400000, 2) int32
  const float* Kmat  = (const float*)d_in[3];   // (16, 1024) f32
  const float* bias  = (const float*)d_in[4];   // (1024,) f32
  float* out = (float*)d_out;                   // (100000, 32) f32

  zero_out<<<(out_size + 255) / 256, 256, 0, stream>>>(out, out_size);
  edge_kernel<<<1024, 256, 0, stream>>>(atom, bondf, pairs, Kmat, bias, out);
}

// Round 2
// 161.179 us; speedup vs baseline: 2.2981x; 2.2981x over previous
//
#include <hip/hip_runtime.h>

// EdgeNetwork as OUT = P @ W on matrix cores (fp16 inputs, fp32 accum):
//   P[e, b*32+j] = bond[e,b] * nb[e,j]   (b = 16 is the bias row, bond == 1)
//   W[b*32+j, i] = K[b, i*32+j]          (b = 16 -> bias[i*32+j])
// K-steps are b-major (K=32 per step, 17 steps), so the A-fragment for step b
// is splat(bond[b]) * nb_frag -- 4 v_pk_mul_f16. W lives in LDS pre-packed in
// B-fragment layout. Epilogue: atomic scatter-add into out[src].

typedef _Float16 half8 __attribute__((ext_vector_type(8)));
typedef float float4v __attribute__((ext_vector_type(4)));

constexpr int E = 400000;
constexpr int BLOCKS = E / 128;   // 3125 blocks x 128 edges (4 waves x 32 edges)

__global__ void zero_out(float* __restrict__ out, int n) {
  int i = blockIdx.x * blockDim.x + threadIdx.x;
  if (i < n) out[i] = 0.0f;
}

static __device__ inline half8 splat8(_Float16 v) {
  half8 r = {v, v, v, v, v, v, v, v};
  return r;
}

__global__ __launch_bounds__(256, 4)
void edge_mfma(const float* __restrict__ atom,
               const float* __restrict__ bondf,
               const int* __restrict__ pairs,
               const float* __restrict__ Kmat,
               const float* __restrict__ bias,
               float* __restrict__ out)
{
  // B-fragments: Wf[step*128 + h*64 + lane] is the half8 B-frag for K-step
  // `step`, column-half h, for `lane`. B[k][n]: n = lane&15 (+16h), k = (lane>>4)*8 + j.
  __shared__ half8 Wf[17 * 2 * 64];   // 34816 B
  const int tid = threadIdx.x;

  for (int idx = tid; idx < 17 * 128; idx += 256) {
    const int step = idx >> 7;          // 0..16
    const int lane = idx & 63;
    const int h    = (idx >> 6) & 1;
    const int q    = lane >> 4;
    const int n    = (lane & 15) + h * 16;  // output col i
    const int j0   = q * 8;
    const float* src = (step < 16) ? (Kmat + step * 1024 + n * 32 + j0)
                                   : (bias + n * 32 + j0);
    half8 w;
    #pragma unroll
    for (int j = 0; j < 8; ++j) w[j] = (_Float16)src[j];
    Wf[idx] = w;
  }
  __syncthreads();

  const int lane = tid & 63;
  const int wave = tid >> 6;
  const int q    = lane >> 4;     // quad 0..3
  const int el   = lane & 15;     // edge-within-tile for A-side
  const int ebase = blockIdx.x * 128 + wave * 32;

  // A-side: this lane supplies P rows for edge eA (tile 0) and eB (tile 1).
  const int eA = ebase + el;
  const int eB = eA + 16;
  const int aA = pairs[2 * eA + 1];
  const int aB = pairs[2 * eB + 1];

  // nb fragment (fixed across all K-steps): nb[e][q*8 + j], j=0..7, f16.
  half8 nbA, nbB;
  {
    const float* pa = atom + (size_t)aA * 32 + q * 8;
    const float* pb = atom + (size_t)aB * 32 + q * 8;
    #pragma unroll
    for (int j = 0; j < 8; ++j) {
      nbA[j] = (_Float16)pa[j];
      nbB[j] = (_Float16)pb[j];
    }
  }
  // bond rows, f16
  _Float16 bondA[16], bondB[16];
  {
    const float* ba = bondf + (size_t)eA * 16;
    const float* bb = bondf + (size_t)eB * 16;
    #pragma unroll
    for (int b = 0; b < 16; ++b) {
      bondA[b] = (_Float16)ba[b];
      bondB[b] = (_Float16)bb[b];
    }
  }

  float4v acc00 = {0.f, 0.f, 0.f, 0.f};
  float4v acc01 = {0.f, 0.f, 0.f, 0.f};
  float4v acc10 = {0.f, 0.f, 0.f, 0.f};
  float4v acc11 = {0.f, 0.f, 0.f, 0.f};

  #pragma unroll
  for (int b = 0; b < 16; ++b) {
    const half8 aAf = nbA * splat8(bondA[b]);   // 4x v_pk_mul_f16
    const half8 aBf = nbB * splat8(bondB[b]);
    const half8 b0 = Wf[b * 128 + lane];
    const half8 b1 = Wf[b * 128 + 64 + lane];
    acc00 = __builtin_amdgcn_mfma_f32_16x16x32_f16(aAf, b0, acc00, 0, 0, 0);
    acc01 = __builtin_amdgcn_mfma_f32_16x16x32_f16(aAf, b1, acc01, 0, 0, 0);
    acc10 = __builtin_amdgcn_mfma_f32_16x16x32_f16(aBf, b0, acc10, 0, 0, 0);
    acc11 = __builtin_amdgcn_mfma_f32_16x16x32_f16(aBf, b1, acc11, 0, 0, 0);
  }
  {   // bias step: bond weight = 1
    const half8 b0 = Wf[16 * 128 + lane];
    const half8 b1 = Wf[16 * 128 + 64 + lane];
    acc00 = __builtin_amdgcn_mfma_f32_16x16x32_f16(nbA, b0, acc00, 0, 0, 0);
    acc01 = __builtin_amdgcn_mfma_f32_16x16x32_f16(nbA, b1, acc01, 0, 0, 0);
    acc10 = __builtin_amdgcn_mfma_f32_16x16x32_f16(nbB, b0, acc10, 0, 0, 0);
    acc11 = __builtin_amdgcn_mfma_f32_16x16x32_f16(nbB, b1, acc11, 0, 0, 0);
  }

  // Epilogue: C[m][n] with m = q*4 + reg (edge within tile), n = lane&15 (+16h).
  const int n = lane & 15;
  #pragma unroll
  for (int r = 0; r < 4; ++r) {
    const int e0 = ebase + q * 4 + r;
    const int s0 = pairs[2 * e0];
    float* o0 = out + (size_t)s0 * 32 + n;
    atomicAdd(o0,      acc00[r]);
    atomicAdd(o0 + 16, acc01[r]);

    const int e1 = e0 + 16;
    const int s1 = pairs[2 * e1];
    float* o1 = out + (size_t)s1 * 32 + n;
    atomicAdd(o1,      acc10[r]);
    atomicAdd(o1 + 16, acc11[r]);
  }
}

extern "C" void kernel_launch(void* const* d_in, const int* in_sizes, int n_in,
                              void* d_out, int out_size, void* d_ws, size_t ws_size,
                              hipStream_t stream) {
  const float* atom  = (const float*)d_in[0];   // (100000, 32) f32
  const float* bondf = (const float*)d_in[1];   // (400000, 16) f32
  const int*   pairs = (const int*)d_in[2];     // (400000, 2) int32
  const float* Kmat  = (const float*)d_in[3];   // (16, 1024) f32
  const float* bias  = (const float*)d_in[4];   // (1024,) f32
  float* out = (float*)d_out;                   // (100000, 32) f32

  zero_out<<<(out_size + 255) / 256, 256, 0, stream>>>(out, out_size);
  edge_mfma<<<BLOCKS, 256, 0, stream>>>(atom, bondf, pairs, Kmat, bias, out);
}

// Round 3
// 154.765 us; speedup vs baseline: 2.3933x; 1.0414x over previous
//
#include <hip/hip_runtime.h>

// EdgeNetwork as OUT = P @ W on matrix cores, W held entirely in VGPRs.
//   P[e, b*32+j] = bond[e,b] * nb[e,j]   (b = 16 is the bias row, bond == 1)
//   W[b*32+j, i] = K[b, i*32+j]          (b = 16 -> bias[i*32+j])
// Persistent grid-stride waves, no LDS, no barriers. Each wave: 32 edges x 16
// output cols (wave parity = column half). K-steps b-major: A-frag for step b
// = splat(bond[b]) * nb_frag (4x v_pk_mul_f16). Epilogue: fire-and-forget
// fp32 atomics, overlapped with next tile's loads.

typedef _Float16 half8 __attribute__((ext_vector_type(8)));
typedef float float4v __attribute__((ext_vector_type(4)));

constexpr int E = 400000;
constexpr int TILES = E / 32;      // 12500 tiles of 32 edges
constexpr int NBLK = 1024;
constexpr int WAVES = NBLK * 4;    // 4096 waves
constexpr int HALFW = WAVES / 2;   // 2048 waves per column-half

__global__ void zero_out4(float4* __restrict__ out, int n4) {
  int i = blockIdx.x * blockDim.x + threadIdx.x;
  if (i < n4) out[i] = make_float4(0.f, 0.f, 0.f, 0.f);
}

static __device__ inline half8 splat8(_Float16 v) {
  half8 r = {v, v, v, v, v, v, v, v};
  return r;
}

__global__ __launch_bounds__(256, 3)
void edge_mfma(const float* __restrict__ atom,
               const float* __restrict__ bondf,
               const int* __restrict__ pairs,
               const float* __restrict__ Kmat,
               const float* __restrict__ bias,
               float* __restrict__ out)
{
  const int tid   = threadIdx.x;
  const int lane  = tid & 63;
  const int wslot = tid >> 6;
  const int wid   = blockIdx.x * 4 + wslot;   // 0..4095
  const int h     = wid & 1;                  // column half this wave owns
  const int q     = lane >> 4;                // quad 0..3
  const int el    = lane & 15;
  const int n     = el + h * 16;              // global output column
  const int j0    = q * 8;

  // B-fragments for all 17 K-steps, resident in registers (17 x 4 VGPRs).
  // B[k][n] with k = q*8 + j: element j = Kmat[s*1024 + n*32 + q*8 + j].
  half8 Wr[17];
  #pragma unroll
  for (int s = 0; s < 17; ++s) {
    const float* src = (s < 16) ? (Kmat + s * 1024 + n * 32 + j0)
                                : (bias + n * 32 + j0);
    half8 w;
    #pragma unroll
    for (int j = 0; j < 8; ++j) w[j] = (_Float16)src[j];
    Wr[s] = w;
  }

  for (int tile = (wid >> 1); tile < TILES; tile += HALFW) {
    const int ebase = tile * 32;

    // One pairs dword per lane covers all 64 indices this tile needs:
    // lane<32 -> src of edge ebase+lane; lane>=32 -> nbr of edge ebase+lane-32.
    int pv;
    if (lane < 32) pv = pairs[2 * (ebase + lane)];
    else           pv = pairs[2 * (ebase + lane - 32) + 1];
    const int aA = __shfl(pv, 32 + el);
    const int aB = __shfl(pv, 32 + el + 16);

    // Neighbor fragments (A-side k-slice), f16.
    half8 nbA, nbB;
    {
      const float* pa = atom + (size_t)aA * 32 + j0;
      const float* pb = atom + (size_t)aB * 32 + j0;
      #pragma unroll
      for (int j = 0; j < 8; ++j) {
        nbA[j] = (_Float16)pa[j];
        nbB[j] = (_Float16)pb[j];
      }
    }
    // Bond rows for this lane's A-row (m = el), f16.
    _Float16 bA[16], bB[16];
    {
      const float* ba = bondf + (size_t)(ebase + el) * 16;
      const float* bb = bondf + (size_t)(ebase + el + 16) * 16;
      #pragma unroll
      for (int b = 0; b < 16; ++b) {
        bA[b] = (_Float16)ba[b];
        bB[b] = (_Float16)bb[b];
      }
    }

    float4v acc0 = {0.f, 0.f, 0.f, 0.f};
    float4v acc1 = {0.f, 0.f, 0.f, 0.f};
    #pragma unroll
    for (int s = 0; s < 16; ++s) {
      const half8 aAf = nbA * splat8(bA[s]);
      const half8 aBf = nbB * splat8(bB[s]);
      acc0 = __builtin_amdgcn_mfma_f32_16x16x32_f16(aAf, Wr[s], acc0, 0, 0, 0);
      acc1 = __builtin_amdgcn_mfma_f32_16x16x32_f16(aBf, Wr[s], acc1, 0, 0, 0);
    }
    // Bias step (bond weight == 1).
    acc0 = __builtin_amdgcn_mfma_f32_16x16x32_f16(nbA, Wr[16], acc0, 0, 0, 0);
    acc1 = __builtin_amdgcn_mfma_f32_16x16x32_f16(nbB, Wr[16], acc1, 0, 0, 0);

    // Epilogue: C row = q*4 + r (edge), col = el (+16h). Fire-and-forget.
    #pragma unroll
    for (int r = 0; r < 4; ++r) {
      const int s0 = __shfl(pv, q * 4 + r);
      atomicAdd(out + (size_t)s0 * 32 + n, acc0[r]);
      const int s1 = __shfl(pv, q * 4 + r + 16);
      atomicAdd(out + (size_t)s1 * 32 + n, acc1[r]);
    }
  }
}

extern "C" void kernel_launch(void* const* d_in, const int* in_sizes, int n_in,
                              void* d_out, int out_size, void* d_ws, size_t ws_size,
                              hipStream_t stream) {
  const float* atom  = (const float*)d_in[0];   // (100000, 32) f32
  const float* bondf = (const float*)d_in[1];   // (400000, 16) f32
  const int*   pairs = (const int*)d_in[2];     // (400000, 2) int32
  const float* Kmat  = (const float*)d_in[3];   // (16, 1024) f32
  const float* bias  = (const float*)d_in[4];   // (1024,) f32
  float* out = (float*)d_out;                   // (100000, 32) f32

  const int n4 = out_size / 4;
  zero_out4<<<(n4 + 255) / 256, 256, 0, stream>>>((float4*)out, n4);
  edge_mfma<<<NBLK, 256, 0, stream>>>(atom, bondf, pairs, Kmat, bias, out);
}